// Round 17
// baseline (767.404 us; speedup 1.0000x reference)
//
#include <hip/hip_runtime.h>
#include <cstdint>
#include <cstddef>

#define N_VARS   4000
#define N_LITS   8000
#define N_CLAUSES 16000
#define N_CELLS  48000
#define DIM      128
#define N_ROUNDS 16
#define N_PROBS  8

typedef __bf16 bf16x8 __attribute__((ext_vector_type(8)));
typedef float f32x4 __attribute__((ext_vector_type(4)));

__device__ inline unsigned short f2bf(float x) {
  unsigned int u = __float_as_uint(x);
  u += 0x7fffu + ((u >> 16) & 1u);          // RTNE
  return (unsigned short)(u >> 16);
}
__device__ inline float bflo(unsigned int v) { return __uint_as_float(v << 16); }
__device__ inline float bfhi(unsigned int v) { return __uint_as_float(v & 0xffff0000u); }
__device__ inline unsigned int pack2(float a, float b) {
  return (unsigned int)f2bf(a) | ((unsigned int)f2bf(b) << 16);
}
__device__ inline bf16x8 ld_frag(const unsigned short* p) {
  uint4 u = *reinterpret_cast<const uint4*>(p);
  return __builtin_bit_cast(bf16x8, u);
}
__device__ inline float fast_sigmoid(float x) { return 1.f / (1.f + __expf(-x)); }
__device__ inline float fast_tanh(float x) {
  float t = __expf(-2.f * x);
  return (1.f - t) / (1.f + t);
}
// pack 4 floats -> 4 OCP e4m3 bytes (one word)
__device__ inline unsigned int pk_fp8x4(float a, float b, float c, float d) {
  int w0 = __builtin_amdgcn_cvt_pk_fp8_f32(a, b, 0, false);
  w0 = __builtin_amdgcn_cvt_pk_fp8_f32(c, d, w0, true);
  return (unsigned int)w0;
}

// Weight tile layouts:
//  gates Wp8 (fp8): 16(row)x32(k) tile = 512B contiguous; lane l reads 8B at
//  tile_base + l*8; tile id = (w*KS + ks)*4 + tt.
//  mlp Wm (bf16): 1KB tiles, tile id = tt*4 + ks.

// ===========================================================================
// fused_round<KS, RG, LIT>: one half-round, ROWS=RG*16 rows/block, 512 thr
// = 8 waves.
// r17: BOTH sides RG=1 (C grid 1000, L grid 500). fp8 W' halves per-block W
// bytes, so C at grid 1000 has the SAME W' L2 traffic as r12's best config
// while doubling co-resident blocks (4/CU) -> phase overlap. This is the
// r13-occupancy lever with its traffic penalty canceled by r16's fp8.
// ===========================================================================
template<int KS, int RG, bool LIT>
__global__ __launch_bounds__(512, 4) void fused_round(
    const int* __restrict__ ptr, const int* __restrict__ col,
    const unsigned short* __restrict__ Tsrc,
    const unsigned short* hold, unsigned short* hnew,   // may alias (C side)
    unsigned short* __restrict__ cst,                   // bf16 cell state
    const unsigned char* __restrict__ Wp8, const float* __restrict__ bP,
    const unsigned short* __restrict__ Wm1, const float* __restrict__ bm1,
    const unsigned short* __restrict__ Wm2, const float* __restrict__ bm2,
    const unsigned short* __restrict__ Wm3, const float* __restrict__ bm3,
    unsigned short* __restrict__ Tout) {
  constexpr int ROWS = RG * 16;
  __shared__ __align__(16) unsigned short msg[ROWS][136];   // scratch + h_new
  __shared__ __align__(16) unsigned short xb[ROWS][136];
  __shared__ __align__(16) unsigned short yb[ROWS][136];
  __shared__ __align__(16) unsigned char  msgq[ROWS][136];  // fp8 gates input
  __shared__ __align__(16) unsigned char  hsAq[ROWS][136];
  __shared__ __align__(16) unsigned char  hsFq[LIT ? ROWS : 1][136];
  __shared__ __align__(16) unsigned short pmsg[RG == 1 ? 3 : 1][RG == 1 ? 16 : 1][136];
  const int tid = threadIdx.x;
  const int w = tid >> 6, l = tid & 63;
  const int r = l & 15, kc = l >> 4;
  const int row0 = blockIdx.x * ROWS;

  // ---- early-issue: h staging loads into regs (threads 256+) ----
  uint4 stA[2], stF[2];
  if (tid >= 256) {
    const int sidx = tid - 256;
#pragma unroll
    for (int q = 0; q < RG; ++q) {
      const int n = sidx + q * 256;          // ROWS x 16 slots of 8 dims
      const int rw = n >> 4, c8 = (n & 15) * 8;
      stA[q] = *reinterpret_cast<const uint4*>(&hold[(size_t)(row0 + rw) * 128 + c8]);
      if (LIT) {
        const int gr = row0 + rw;
        const int fr = (gr < N_VARS) ? gr + N_VARS : gr - N_VARS;
        stF[q] = *reinterpret_cast<const uint4*>(&hold[(size_t)fr * 128 + c8]);
      }
    }
  }

  // ---- phase 1a: split gather (8-lane groups, 16 dims/lane), fp32 regs ----
  float s[16];
  {
    const int g8 = tid >> 3, gl = tid & 7;
    const int grow = (RG == 2) ? (g8 & 31) : (g8 & 15);
    const int part = (RG == 2) ? (g8 >> 5) : (g8 >> 4);
    constexpr int NPART = (RG == 2) ? 2 : 4;
    const int row = row0 + grow;
    const int b = ptr[row], e = ptr[row + 1];
#pragma unroll
    for (int q = 0; q < 16; ++q) s[q] = 0.f;
    int j = b + part;
    int c0 = (j < e) ? col[j] : 0;
    while (j < e) {
      const int jn = j + NPART;
      const int c1 = (jn < e) ? col[jn] : 0;
      const unsigned short* src = &Tsrc[(size_t)c0 * 128 + gl * 16];
      const uint4 v0 = *reinterpret_cast<const uint4*>(src);
      const uint4 v1 = *reinterpret_cast<const uint4*>(src + 8);
      s[0]  += bflo(v0.x); s[1]  += bfhi(v0.x);
      s[2]  += bflo(v0.y); s[3]  += bfhi(v0.y);
      s[4]  += bflo(v0.z); s[5]  += bfhi(v0.z);
      s[6]  += bflo(v0.w); s[7]  += bfhi(v0.w);
      s[8]  += bflo(v1.x); s[9]  += bfhi(v1.x);
      s[10] += bflo(v1.y); s[11] += bfhi(v1.y);
      s[12] += bflo(v1.z); s[13] += bfhi(v1.z);
      s[14] += bflo(v1.w); s[15] += bfhi(v1.w);
      j = jn; c0 = c1;
    }
    if (part > 0) {    // write bf16 partial to scratch
      uint4 o0, o1;
      o0.x = pack2(s[0], s[1]);  o0.y = pack2(s[2], s[3]);
      o0.z = pack2(s[4], s[5]);  o0.w = pack2(s[6], s[7]);
      o1.x = pack2(s[8], s[9]);  o1.y = pack2(s[10], s[11]);
      o1.z = pack2(s[12], s[13]); o1.w = pack2(s[14], s[15]);
      unsigned short* dst = (RG == 2) ? &msg[grow][gl * 16]
                                      : &pmsg[part - 1][grow][gl * 16];
      *reinterpret_cast<uint4*>(dst) = o0;
      *reinterpret_cast<uint4*>(dst + 8) = o1;
    }
  }
  __syncthreads();

  // ---- phase 1b: part 0 combines -> fp8 msgq; threads 256+ stage h fp8 ----
  {
    const int g8 = tid >> 3, gl = tid & 7;
    const int grow = (RG == 2) ? (g8 & 31) : (g8 & 15);
    const int part = (RG == 2) ? (g8 >> 5) : (g8 >> 4);
    if (part == 0) {
      if (RG == 2) {
        const uint4 m0 = *reinterpret_cast<const uint4*>(&msg[grow][gl * 16]);
        const uint4 m1 = *reinterpret_cast<const uint4*>(&msg[grow][gl * 16 + 8]);
        s[0]  += bflo(m0.x); s[1]  += bfhi(m0.x);
        s[2]  += bflo(m0.y); s[3]  += bfhi(m0.y);
        s[4]  += bflo(m0.z); s[5]  += bfhi(m0.z);
        s[6]  += bflo(m0.w); s[7]  += bfhi(m0.w);
        s[8]  += bflo(m1.x); s[9]  += bfhi(m1.x);
        s[10] += bflo(m1.y); s[11] += bfhi(m1.y);
        s[12] += bflo(m1.z); s[13] += bfhi(m1.z);
        s[14] += bflo(m1.w); s[15] += bfhi(m1.w);
      } else {
#pragma unroll
        for (int p = 0; p < 3; ++p) {
          const uint4 m0 = *reinterpret_cast<const uint4*>(&pmsg[p][grow][gl * 16]);
          const uint4 m1 = *reinterpret_cast<const uint4*>(&pmsg[p][grow][gl * 16 + 8]);
          s[0]  += bflo(m0.x); s[1]  += bfhi(m0.x);
          s[2]  += bflo(m0.y); s[3]  += bfhi(m0.y);
          s[4]  += bflo(m0.z); s[5]  += bfhi(m0.z);
          s[6]  += bflo(m0.w); s[7]  += bfhi(m0.w);
          s[8]  += bflo(m1.x); s[9]  += bfhi(m1.x);
          s[10] += bflo(m1.y); s[11] += bfhi(m1.y);
          s[12] += bflo(m1.z); s[13] += bfhi(m1.z);
          s[14] += bflo(m1.w); s[15] += bfhi(m1.w);
        }
      }
      uint4 o;
      o.x = pk_fp8x4(s[0], s[1], s[2], s[3]);
      o.y = pk_fp8x4(s[4], s[5], s[6], s[7]);
      o.z = pk_fp8x4(s[8], s[9], s[10], s[11]);
      o.w = pk_fp8x4(s[12], s[13], s[14], s[15]);
      *reinterpret_cast<uint4*>(&msgq[grow][gl * 16]) = o;
    } else if (tid >= 256) {
      const int sidx = tid - 256;
#pragma unroll
      for (int q = 0; q < RG; ++q) {
        const int n = sidx + q * 256;
        const int rw = n >> 4, c8 = (n & 15) * 8;
        {
          uint2 o;
          o.x = pk_fp8x4(bflo(stA[q].x), bfhi(stA[q].x), bflo(stA[q].y), bfhi(stA[q].y));
          o.y = pk_fp8x4(bflo(stA[q].z), bfhi(stA[q].z), bflo(stA[q].w), bfhi(stA[q].w));
          *reinterpret_cast<uint2*>(&hsAq[rw][c8]) = o;
        }
        if (LIT) {
          uint2 o;
          o.x = pk_fp8x4(bflo(stF[q].x), bfhi(stF[q].x), bflo(stF[q].y), bfhi(stF[q].y));
          o.y = pk_fp8x4(bflo(stF[q].z), bfhi(stF[q].z), bflo(stF[q].w), bfhi(stF[q].w));
          *reinterpret_cast<uint2*>(&hsFq[rw][c8]) = o;
        }
      }
    }
  }
  __syncthreads();

  // ---- phase 2: gates GEMM in fp8 (512B W tiles) ----
  f32x4 acc[RG][4];
#pragma unroll
  for (int rg = 0; rg < RG; ++rg)
#pragma unroll
    for (int t = 0; t < 4; ++t) acc[rg][t] = (f32x4){0.f, 0.f, 0.f, 0.f};

#pragma unroll
  for (int ks = 0; ks < KS; ++ks) {
    long bfr[RG];
#pragma unroll
    for (int rg = 0; rg < RG; ++rg) {
      const int xr = rg * 16 + r;
      const unsigned char* src;
      if (ks < 4)        src = &msgq[xr][ks * 32 + kc * 8];
      else if (!LIT)     src = &hsAq[xr][(ks - 4) * 32 + kc * 8];
      else if (ks < 8)   src = &hsFq[xr][(ks - 4) * 32 + kc * 8];
      else               src = &hsAq[xr][(ks - 8) * 32 + kc * 8];
      bfr[rg] = *reinterpret_cast<const long*>(src);
    }
#pragma unroll
    for (int tt = 0; tt < 4; ++tt) {
      const long afr = *reinterpret_cast<const long*>(
          &Wp8[(size_t)(((w * KS + ks) * 4 + tt) * 64 + l) * 8]);
#pragma unroll
      for (int rg = 0; rg < RG; ++rg)
        acc[rg][tt] = __builtin_amdgcn_mfma_f32_16x16x32_fp8_fp8(afr, bfr[rg], acc[rg][tt], 0, 0, 0);
    }
  }
  // no barrier needed: epilogue writes msg (dead) / global only

  // ---- LSTM epilogue (zero-shuffle; h_new -> bf16 `msg` for phase 3) ----
  {
    const int d0 = w * 16 + kc * 4;
#pragma unroll
    for (int rg = 0; rg < RG; ++rg) {
      const int row = row0 + rg * 16 + r;
      const size_t cb = (size_t)row * 128 + d0;
      const uint2 cv2 = *reinterpret_cast<const uint2*>(&cst[cb]);
      const float cpv[4] = {bflo(cv2.x), bfhi(cv2.x), bflo(cv2.y), bfhi(cv2.y)};
      unsigned int cp2[2], hp[2];
#pragma unroll
      for (int tt = 0; tt < 4; ++tt) {
        const float4 bb = *reinterpret_cast<const float4*>(&bP[w * 64 + tt * 16 + kc * 4]);
        float ig = acc[rg][tt][0] + bb.x;
        float fg = acc[rg][tt][1] + bb.y;
        float gg = acc[rg][tt][2] + bb.z;
        float og = acc[rg][tt][3] + bb.w;
        float cn = fast_sigmoid(fg) * cpv[tt] + fast_sigmoid(ig) * fast_tanh(gg);
        float hv = fast_sigmoid(og) * fast_tanh(cn);
        if (tt & 1) { cp2[tt >> 1] |= (unsigned int)f2bf(cn) << 16;
                      hp[tt >> 1]  |= (unsigned int)f2bf(hv) << 16; }
        else        { cp2[tt >> 1]  = (unsigned int)f2bf(cn);
                      hp[tt >> 1]   = (unsigned int)f2bf(hv); }
      }
      uint2 cw = {cp2[0], cp2[1]};
      *reinterpret_cast<uint2*>(&cst[cb]) = cw;
      uint2 hv2 = {hp[0], hp[1]};
      *reinterpret_cast<uint2*>(&hnew[cb]) = hv2;
      *reinterpret_cast<uint2*>(&msg[rg * 16 + r][d0]) = hv2;
    }
  }
  __syncthreads();

  // ---- phase 3: 3-layer MLP (bf16); wave w = col-tile w, rg looped ----
  {
    f32x4 a2[RG];
#pragma unroll
    for (int rg = 0; rg < RG; ++rg) a2[rg] = (f32x4){0.f, 0.f, 0.f, 0.f};
#pragma unroll
    for (int ks = 0; ks < 4; ++ks) {
      bf16x8 bf = ld_frag(&Wm1[(size_t)((w * 4 + ks) * 64 + l) * 8]);
#pragma unroll
      for (int rg = 0; rg < RG; ++rg) {
        bf16x8 af = ld_frag(&msg[rg * 16 + r][ks * 32 + kc * 8]);
        a2[rg] = __builtin_amdgcn_mfma_f32_16x16x32_bf16(af, bf, a2[rg], 0, 0, 0);
      }
    }
    float bv = bm1[w * 16 + r];
#pragma unroll
    for (int rg = 0; rg < RG; ++rg)
#pragma unroll
      for (int j = 0; j < 4; ++j)
        xb[rg * 16 + kc * 4 + j][w * 16 + r] = f2bf(fmaxf(a2[rg][j] + bv, 0.f));
  }
  __syncthreads();
  {
    f32x4 a2[RG];
#pragma unroll
    for (int rg = 0; rg < RG; ++rg) a2[rg] = (f32x4){0.f, 0.f, 0.f, 0.f};
#pragma unroll
    for (int ks = 0; ks < 4; ++ks) {
      bf16x8 bf = ld_frag(&Wm2[(size_t)((w * 4 + ks) * 64 + l) * 8]);
#pragma unroll
      for (int rg = 0; rg < RG; ++rg) {
        bf16x8 af = ld_frag(&xb[rg * 16 + r][ks * 32 + kc * 8]);
        a2[rg] = __builtin_amdgcn_mfma_f32_16x16x32_bf16(af, bf, a2[rg], 0, 0, 0);
      }
    }
    float bv = bm2[w * 16 + r];
    __syncthreads();
#pragma unroll
    for (int rg = 0; rg < RG; ++rg)
#pragma unroll
      for (int j = 0; j < 4; ++j)
        yb[rg * 16 + kc * 4 + j][w * 16 + r] = f2bf(fmaxf(a2[rg][j] + bv, 0.f));
  }
  __syncthreads();
  {
    f32x4 a2[RG];
#pragma unroll
    for (int rg = 0; rg < RG; ++rg) a2[rg] = (f32x4){0.f, 0.f, 0.f, 0.f};
#pragma unroll
    for (int ks = 0; ks < 4; ++ks) {
      bf16x8 bf = ld_frag(&Wm3[(size_t)((w * 4 + ks) * 64 + l) * 8]);
#pragma unroll
      for (int rg = 0; rg < RG; ++rg) {
        bf16x8 af = ld_frag(&yb[rg * 16 + r][ks * 32 + kc * 8]);
        a2[rg] = __builtin_amdgcn_mfma_f32_16x16x32_bf16(af, bf, a2[rg], 0, 0, 0);
      }
    }
    float bv = bm3[w * 16 + r];
#pragma unroll
    for (int rg = 0; rg < RG; ++rg)
#pragma unroll
      for (int j = 0; j < 4; ++j)
        Tout[(size_t)(row0 + rg * 16 + kc * 4 + j) * 128 + w * 16 + r] =
            f2bf(a2[rg][j] + bv);
  }
}

// ---------------------------------------------------------------------------
// Prologue 3-layer MLP (tiled bf16 weights): 256 thr = 4 waves, 64 rows.
// ---------------------------------------------------------------------------
__global__ __launch_bounds__(256) void fused_mlp3(
    const unsigned short* __restrict__ A,
    const unsigned short* __restrict__ W1, const float* __restrict__ b1,
    const unsigned short* __restrict__ W2, const float* __restrict__ b2,
    const unsigned short* __restrict__ W3, const float* __restrict__ b3,
    unsigned short* __restrict__ out) {
  __shared__ __align__(16) unsigned short xbuf[2][4][16][136];
  const int w = threadIdx.x >> 6, l = threadIdx.x & 63;
  const int r = l & 15, kc = l >> 4;
  const int row0 = blockIdx.x * 64 + w * 16;

  f32x4 acc[8];
#pragma unroll
  for (int t = 0; t < 8; ++t) acc[t] = (f32x4){0.f, 0.f, 0.f, 0.f};
#pragma unroll
  for (int ks = 0; ks < 4; ++ks) {
    bf16x8 a = ld_frag(&A[(size_t)(row0 + r) * 128 + ks * 32 + kc * 8]);
#pragma unroll
    for (int t = 0; t < 8; ++t) {
      bf16x8 b = ld_frag(&W1[(size_t)((t * 4 + ks) * 64 + l) * 8]);
      acc[t] = __builtin_amdgcn_mfma_f32_16x16x32_bf16(a, b, acc[t], 0, 0, 0);
    }
  }
#pragma unroll
  for (int t = 0; t < 8; ++t) {
    float bv = b1[t * 16 + r];
#pragma unroll
    for (int j = 0; j < 4; ++j)
      xbuf[0][w][kc * 4 + j][t * 16 + r] = f2bf(fmaxf(acc[t][j] + bv, 0.f));
  }
#pragma unroll
  for (int t = 0; t < 8; ++t) acc[t] = (f32x4){0.f, 0.f, 0.f, 0.f};
#pragma unroll
  for (int ks = 0; ks < 4; ++ks) {
    bf16x8 a = ld_frag(&xbuf[0][w][r][ks * 32 + kc * 8]);
#pragma unroll
    for (int t = 0; t < 8; ++t) {
      bf16x8 b = ld_frag(&W2[(size_t)((t * 4 + ks) * 64 + l) * 8]);
      acc[t] = __builtin_amdgcn_mfma_f32_16x16x32_bf16(a, b, acc[t], 0, 0, 0);
    }
  }
#pragma unroll
  for (int t = 0; t < 8; ++t) {
    float bv = b2[t * 16 + r];
#pragma unroll
    for (int j = 0; j < 4; ++j)
      xbuf[1][w][kc * 4 + j][t * 16 + r] = f2bf(fmaxf(acc[t][j] + bv, 0.f));
  }
#pragma unroll
  for (int t = 0; t < 8; ++t) acc[t] = (f32x4){0.f, 0.f, 0.f, 0.f};
#pragma unroll
  for (int ks = 0; ks < 4; ++ks) {
    bf16x8 a = ld_frag(&xbuf[1][w][r][ks * 32 + kc * 8]);
#pragma unroll
    for (int t = 0; t < 8; ++t) {
      bf16x8 b = ld_frag(&W3[(size_t)((t * 4 + ks) * 64 + l) * 8]);
      acc[t] = __builtin_amdgcn_mfma_f32_16x16x32_bf16(a, b, acc[t], 0, 0, 0);
    }
  }
#pragma unroll
  for (int t = 0; t < 8; ++t) {
    float bv = b3[t * 16 + r];
#pragma unroll
    for (int j = 0; j < 4; ++j)
      out[(size_t)(row0 + kc * 4 + j) * 128 + t * 16 + r] = f2bf(acc[t][j] + bv);
  }
}

// ---------------------------------------------------------------------------
// Fused vote (tiled bf16 weights).
// ---------------------------------------------------------------------------
__global__ __launch_bounds__(256) void fused_vote(
    const unsigned short* __restrict__ A,
    const unsigned short* __restrict__ W1, const float* __restrict__ b1,
    const unsigned short* __restrict__ W2, const float* __restrict__ b2,
    const float* __restrict__ w3, const float* __restrict__ b3,
    float* __restrict__ vote) {
  __shared__ __align__(16) unsigned short xbuf[4][16][136];
  const int w = threadIdx.x >> 6, l = threadIdx.x & 63;
  const int r = l & 15, kc = l >> 4;
  const int row0 = blockIdx.x * 64 + w * 16;

  f32x4 acc[8];
#pragma unroll
  for (int t = 0; t < 8; ++t) acc[t] = (f32x4){0.f, 0.f, 0.f, 0.f};
#pragma unroll
  for (int ks = 0; ks < 4; ++ks) {
    bf16x8 a = ld_frag(&A[(size_t)(row0 + r) * 128 + ks * 32 + kc * 8]);
#pragma unroll
    for (int t = 0; t < 8; ++t) {
      bf16x8 b = ld_frag(&W1[(size_t)((t * 4 + ks) * 64 + l) * 8]);
      acc[t] = __builtin_amdgcn_mfma_f32_16x16x32_bf16(a, b, acc[t], 0, 0, 0);
    }
  }
#pragma unroll
  for (int t = 0; t < 8; ++t) {
    float bv = b1[t * 16 + r];
#pragma unroll
    for (int j = 0; j < 4; ++j)
      xbuf[w][kc * 4 + j][t * 16 + r] = f2bf(fmaxf(acc[t][j] + bv, 0.f));
  }
#pragma unroll
  for (int t = 0; t < 8; ++t) acc[t] = (f32x4){0.f, 0.f, 0.f, 0.f};
#pragma unroll
  for (int ks = 0; ks < 4; ++ks) {
    bf16x8 a = ld_frag(&xbuf[w][r][ks * 32 + kc * 8]);
#pragma unroll
    for (int t = 0; t < 8; ++t) {
      bf16x8 b = ld_frag(&W2[(size_t)((t * 4 + ks) * 64 + l) * 8]);
      acc[t] = __builtin_amdgcn_mfma_f32_16x16x32_bf16(a, b, acc[t], 0, 0, 0);
    }
  }
  float vs[4] = {0.f, 0.f, 0.f, 0.f};
#pragma unroll
  for (int t = 0; t < 8; ++t) {
    float bv = b2[t * 16 + r], wv = w3[t * 16 + r];
#pragma unroll
    for (int j = 0; j < 4; ++j)
      vs[j] += fmaxf(acc[t][j] + bv, 0.f) * wv;
  }
#pragma unroll
  for (int off = 1; off < 16; off <<= 1) {
#pragma unroll
    for (int j = 0; j < 4; ++j) vs[j] += __shfl_xor(vs[j], off, 16);
  }
  if (r == 0) {
#pragma unroll
    for (int j = 0; j < 4; ++j) vote[row0 + kc * 4 + j] = vs[j] + b3[0];
  }
}

// ---------------------------------------------------------------------------
// One-time prep (c state bf16).
// ---------------------------------------------------------------------------
__global__ void init_state_kernel(const float* __restrict__ Lw, const float* __restrict__ Lb,
                                  const float* __restrict__ Cw, const float* __restrict__ Cb,
                                  unsigned short* __restrict__ Lh, unsigned short* __restrict__ Lc,
                                  unsigned short* __restrict__ Ch, unsigned short* __restrict__ Cc) {
  int idx = blockIdx.x * 256 + threadIdx.x;
  if (idx >= N_CLAUSES * DIM) return;
  int d = idx & 127;
  Ch[idx] = f2bf(Cw[d] + Cb[d]);
  Cc[idx] = 0;
  if (idx < N_LITS * DIM) {
    Lh[idx] = f2bf(Lw[d] + Lb[d]);
    Lc[idx] = 0;
  }
}

// 8 fp32 [128,128] matrices -> bf16 tile-packed (tile id = tt*4+ks).
__global__ void pack8_kernel(const float* s0, const float* s1, const float* s2, const float* s3,
                             const float* s4, const float* s5, const float* s6, const float* s7,
                             unsigned short* d0, unsigned short* d1, unsigned short* d2,
                             unsigned short* d3, unsigned short* d4, unsigned short* d5,
                             unsigned short* d6, unsigned short* d7) {
  int i = blockIdx.x * 256 + threadIdx.x;   // [0, 16384)
  const float* s; unsigned short* d;
  switch (blockIdx.y) {
    case 0: s = s0; d = d0; break;
    case 1: s = s1; d = d1; break;
    case 2: s = s2; d = d2; break;
    case 3: s = s3; d = d3; break;
    case 4: s = s4; d = d4; break;
    case 5: s = s5; d = d5; break;
    case 6: s = s6; d = d6; break;
    default: s = s7; d = d7; break;
  }
  int np = i >> 7, k = i & 127;
  int tt = np >> 4, r = np & 15;
  int ks = k >> 5, kcf = (k >> 3) & 3, e = k & 7;
  int dst = (((tt * 4 + ks) * 64) + kcf * 16 + r) * 8 + e;
  d[dst] = f2bf(s[i]);
}

// Gate-permuted + tile-packed LSTM weight pack -> fp8 e4m3 (8-wave layout).
template<int KIH>
__global__ void pack_gates_kernel(const float* __restrict__ wih, const float* __restrict__ whh,
                                  const float* __restrict__ bih, const float* __restrict__ bhh,
                                  unsigned char* __restrict__ Wp8, float* __restrict__ bP) {
  constexpr int K = KIH + 128;
  constexpr int KS = K / 32;
  int idx = blockIdx.x * 256 + threadIdx.x;
  if (idx >= 512 * K) return;
  int np = idx / K, k = idx % K;
  int gt = np & 3;
  int d = ((np >> 6) << 4) + (((np >> 2) & 3) << 2) + ((np >> 4) & 3);
  int orig = gt * 128 + d;
  float v = (k < KIH) ? wih[(size_t)orig * KIH + k] : whh[(size_t)orig * 128 + (k - KIH)];
  int w = np >> 6, tt = (np >> 4) & 3, rr = np & 15;
  int ks = k >> 5, kcf = (k >> 3) & 3, e = k & 7;
  size_t dst = ((size_t)((w * KS + ks) * 4 + tt) * 64 + kcf * 16 + rr) * 8 + e;
  Wp8[dst] = (unsigned char)(__builtin_amdgcn_cvt_pk_fp8_f32(v, 0.f, 0, false) & 0xff);
  if (k == 0) bP[np] = bih[orig] + bhh[orig];
}

// ---------------------------------------------------------------------------
// CSR build.
// ---------------------------------------------------------------------------
__global__ void count_kernel(const int* __restrict__ uidx,
                             int* __restrict__ lit_cnt, int* __restrict__ cls_cnt) {
  int i = blockIdx.x * 256 + threadIdx.x;
  if (i < N_CELLS) {
    atomicAdd(&lit_cnt[uidx[2 * i]], 1);
    atomicAdd(&cls_cnt[uidx[2 * i + 1]], 1);
  }
}

__global__ void scan_kernel(const int* __restrict__ cnt, int* __restrict__ ptr, int n) {
  __shared__ int part[1024];
  __shared__ int total;
  int t = threadIdx.x;
  int chunk = (n + 1023) >> 10;
  int lo = t * chunk, hi = min(lo + chunk, n);
  int s = 0;
  for (int i = lo; i < hi; ++i) s += cnt[i];
  part[t] = s;
  __syncthreads();
  if (t == 0) {
    int acc = 0;
    for (int i = 0; i < 1024; ++i) { int v = part[i]; part[i] = acc; acc += v; }
    total = acc;
  }
  __syncthreads();
  int acc = part[t];
  for (int i = lo; i < hi; ++i) { ptr[i] = acc; acc += cnt[i]; }
  if (t == 0) ptr[n] = total;
}

__global__ void scatter_kernel(const int* __restrict__ uidx,
                               const int* __restrict__ lit_ptr, const int* __restrict__ cls_ptr,
                               int* __restrict__ lit_fill, int* __restrict__ cls_fill,
                               int* __restrict__ lit_col, int* __restrict__ cls_col) {
  int i = blockIdx.x * 256 + threadIdx.x;
  if (i < N_CELLS) {
    int lit = uidx[2 * i], cls = uidx[2 * i + 1];
    int p = atomicAdd(&lit_fill[lit], 1);
    lit_col[lit_ptr[lit] + p] = cls;
    int q = atomicAdd(&cls_fill[cls], 1);
    cls_col[cls_ptr[cls] + q] = lit;
  }
}

__global__ void prob_mean_kernel(const float* __restrict__ vote, float* __restrict__ out) {
  int p = blockIdx.x;
  int t = threadIdx.x;
  float s = 0.f;
  for (int i = t; i < 500; i += 256) s += vote[p * 500 + i] + vote[N_VARS + p * 500 + i];
  __shared__ float red[256];
  red[t] = s;
  __syncthreads();
  for (int off = 128; off > 0; off >>= 1) {
    if (t < off) red[t] += red[t + off];
    __syncthreads();
  }
  if (t == 0) out[p] = red[0] * (1.0f / 1000.0f);
}

// ---------------------------------------------------------------------------
extern "C" void kernel_launch(void* const* d_in, const int* in_sizes, int n_in,
                              void* d_out, int out_size, void* d_ws, size_t ws_size,
                              hipStream_t stream) {
  (void)in_sizes; (void)n_in; (void)out_size;
  const int* uidx = (const int*)d_in[0];
  const float* L_init_w = (const float*)d_in[4];
  const float* L_init_b = (const float*)d_in[5];
  const float* C_init_w = (const float*)d_in[6];
  const float* C_init_b = (const float*)d_in[7];
  const float* Lmsg_w1 = (const float*)d_in[8],  *Lmsg_b1 = (const float*)d_in[9];
  const float* Lmsg_w2 = (const float*)d_in[10], *Lmsg_b2 = (const float*)d_in[11];
  const float* Lmsg_w3 = (const float*)d_in[12], *Lmsg_b3 = (const float*)d_in[13];
  const float* Cmsg_w1 = (const float*)d_in[14], *Cmsg_b1 = (const float*)d_in[15];
  const float* Cmsg_w2 = (const float*)d_in[16], *Cmsg_b2 = (const float*)d_in[17];
  const float* Cmsg_w3 = (const float*)d_in[18], *Cmsg_b3 = (const float*)d_in[19];
  const float* Lvote_w1 = (const float*)d_in[20], *Lvote_b1 = (const float*)d_in[21];
  const float* Lvote_w2 = (const float*)d_in[22], *Lvote_b2 = (const float*)d_in[23];
  const float* Lvote_w3 = (const float*)d_in[24], *Lvote_b3 = (const float*)d_in[25];
  const float* Lu_wih = (const float*)d_in[26], *Lu_whh = (const float*)d_in[27];
  const float* Lu_bih = (const float*)d_in[28], *Lu_bhh = (const float*)d_in[29];
  const float* Cu_wih = (const float*)d_in[30], *Cu_whh = (const float*)d_in[31];
  const float* Cu_bih = (const float*)d_in[32], *Cu_bhh = (const float*)d_in[33];
  float* out = (float*)d_out;

  // ---- workspace carve-up ----
  char* base = (char*)d_ws;
  size_t off = 0;
  auto alloc = [&](size_t bytes) {
    void* p = base + off;
    off = (off + bytes + 255) & ~(size_t)255;
    return p;
  };
  unsigned short* Lc = (unsigned short*)alloc((size_t)N_LITS * DIM * 2);
  unsigned short* Cc = (unsigned short*)alloc((size_t)N_CLAUSES * DIM * 2);
  float* bL   = (float*)alloc(512 * 4);
  float* bC   = (float*)alloc(512 * 4);
  float* vote = (float*)alloc(N_LITS * 4);
  unsigned short* LhA = (unsigned short*)alloc((size_t)N_LITS * DIM * 2);
  unsigned short* LhB = (unsigned short*)alloc((size_t)N_LITS * DIM * 2);
  unsigned short* Ch  = (unsigned short*)alloc((size_t)N_CLAUSES * DIM * 2);
  unsigned short* TL  = (unsigned short*)alloc((size_t)N_LITS * DIM * 2);
  unsigned short* TC  = (unsigned short*)alloc((size_t)N_CLAUSES * DIM * 2);
  unsigned char* WLp8 = (unsigned char*)alloc(512 * 384);
  unsigned char* WCp8 = (unsigned char*)alloc(512 * 256);
  unsigned short* wLm1 = (unsigned short*)alloc(DIM * DIM * 2);
  unsigned short* wLm2 = (unsigned short*)alloc(DIM * DIM * 2);
  unsigned short* wLm3 = (unsigned short*)alloc(DIM * DIM * 2);
  unsigned short* wCm1 = (unsigned short*)alloc(DIM * DIM * 2);
  unsigned short* wCm2 = (unsigned short*)alloc(DIM * DIM * 2);
  unsigned short* wCm3 = (unsigned short*)alloc(DIM * DIM * 2);
  unsigned short* wV1  = (unsigned short*)alloc(DIM * DIM * 2);
  unsigned short* wV2  = (unsigned short*)alloc(DIM * DIM * 2);
  int* lit_cnt  = (int*)alloc(N_LITS * 4);
  int* cls_cnt  = (int*)alloc(N_CLAUSES * 4);
  int* lit_fill = (int*)alloc(N_LITS * 4);
  int* cls_fill = (int*)alloc(N_CLAUSES * 4);
  int* lit_ptr  = (int*)alloc((N_LITS + 1) * 4);
  int* cls_ptr  = (int*)alloc((N_CLAUSES + 1) * 4);
  int* lit_col  = (int*)alloc(N_CELLS * 4);
  int* cls_col  = (int*)alloc(N_CELLS * 4);
  if (off > ws_size) return;

  // ---- CSR build (redone every launch) ----
  hipMemsetAsync(lit_cnt, 0, (char*)lit_ptr - (char*)lit_cnt, stream);
  count_kernel<<<(N_CELLS + 255) / 256, 256, 0, stream>>>(uidx, lit_cnt, cls_cnt);
  scan_kernel<<<1, 1024, 0, stream>>>(lit_cnt, lit_ptr, N_LITS);
  scan_kernel<<<1, 1024, 0, stream>>>(cls_cnt, cls_ptr, N_CLAUSES);
  scatter_kernel<<<(N_CELLS + 255) / 256, 256, 0, stream>>>(
      uidx, lit_ptr, cls_ptr, lit_fill, cls_fill, lit_col, cls_col);

  // ---- one-time weight conversion / packing / state init ----
  init_state_kernel<<<(N_CLAUSES * DIM + 255) / 256, 256, 0, stream>>>(
      L_init_w, L_init_b, C_init_w, C_init_b, LhA, Lc, Ch, Cc);
  pack_gates_kernel<256><<<(512 * 384 + 255) / 256, 256, 0, stream>>>(
      Lu_wih, Lu_whh, Lu_bih, Lu_bhh, WLp8, bL);
  pack_gates_kernel<128><<<(512 * 256 + 255) / 256, 256, 0, stream>>>(
      Cu_wih, Cu_whh, Cu_bih, Cu_bhh, WCp8, bC);
  dim3 cgrid(DIM * DIM / 256, 8);
  pack8_kernel<<<cgrid, 256, 0, stream>>>(
      Lmsg_w1, Lmsg_w2, Lmsg_w3, Cmsg_w1, Cmsg_w2, Cmsg_w3, Lvote_w1, Lvote_w2,
      wLm1, wLm2, wLm3, wCm1, wCm2, wCm3, wV1, wV2);

  // ---- prologue: T_L = L-MLP(Lh0) ----
  fused_mlp3<<<N_LITS / 64, 256, 0, stream>>>(
      LhA, wLm1, Lmsg_b1, wLm2, Lmsg_b2, wLm3, Lmsg_b3, TL);

  // ---- message-passing rounds: 2 kernels per round ----
  for (int r = 0; r < N_ROUNDS; ++r) {
    fused_round<8, 1, false><<<N_CLAUSES / 16, 512, 0, stream>>>(
        cls_ptr, cls_col, TL, Ch, Ch, Cc, WCp8, bC,
        wCm1, Cmsg_b1, wCm2, Cmsg_b2, wCm3, Cmsg_b3, TC);
    const unsigned short* lold = (r & 1) ? LhB : LhA;
    unsigned short* lnew = (r & 1) ? LhA : LhB;
    fused_round<12, 1, true><<<N_LITS / 16, 512, 0, stream>>>(
        lit_ptr, lit_col, TC, lold, lnew, Lc, WLp8, bL,
        wLm1, Lmsg_b1, wLm2, Lmsg_b2, wLm3, Lmsg_b3, TL);
  }
  // after 16 rounds (even count), final Lh is in LhA

  // ---- vote + per-problem mean ----
  fused_vote<<<N_LITS / 64, 256, 0, stream>>>(
      LhA, wV1, Lvote_b1, wV2, Lvote_b2, Lvote_w3, Lvote_b3, vote);
  prob_mean_kernel<<<N_PROBS, 256, 0, stream>>>(vote, out);
}

// Round 18
// 700.919 us; speedup vs baseline: 1.0949x; 1.0949x over previous
//
#include <hip/hip_runtime.h>
#include <cstdint>
#include <cstddef>

#define N_VARS   4000
#define N_LITS   8000
#define N_CLAUSES 16000
#define N_CELLS  48000
#define DIM      128
#define N_ROUNDS 16
#define N_PROBS  8

typedef __bf16 bf16x8 __attribute__((ext_vector_type(8)));
typedef float f32x4 __attribute__((ext_vector_type(4)));

__device__ inline unsigned short f2bf(float x) {
  unsigned int u = __float_as_uint(x);
  u += 0x7fffu + ((u >> 16) & 1u);          // RTNE
  return (unsigned short)(u >> 16);
}
__device__ inline float bflo(unsigned int v) { return __uint_as_float(v << 16); }
__device__ inline float bfhi(unsigned int v) { return __uint_as_float(v & 0xffff0000u); }
__device__ inline unsigned int pack2(float a, float b) {
  return (unsigned int)f2bf(a) | ((unsigned int)f2bf(b) << 16);
}
__device__ inline bf16x8 ld_frag(const unsigned short* p) {
  uint4 u = *reinterpret_cast<const uint4*>(p);
  return __builtin_bit_cast(bf16x8, u);
}
__device__ inline float fast_sigmoid(float x) { return 1.f / (1.f + __expf(-x)); }
__device__ inline float fast_tanh(float x) {
  float t = __expf(-2.f * x);
  return (1.f - t) / (1.f + t);
}

// Weight tile layout: 16(row)x32(k) bf16 MFMA fragment tile = 1KB contiguous;
// lane l reads 16B at tile_base + l*16.
// gates Wp (8-wave): tile id = (w*KS + ks)*4 + tt ; mlp Wm: tile id = tt*4+ks.
// [.][136]-short LDS rows are bank-uniform for all 16B patterns here.

// ===========================================================================
// fused_round<KS, RG, LIT>: one half-round, ROWS=RG*16 rows/block, 512 thr
// = 8 waves. C: RG=2 grid 500; L: RG=1 grid 500 (best measured geometry).
// bf16 cell state (HBM diet); phase-3 Wm single-read per block.
//  2:  gates = [msg|h...] @ Wp^T + bP; wave w owns gate-cols [w*64,(w+1)*64):
//      np = w*64+tt*16+kc*4+j <-> gate j, dim d=w*16+kc*4+tt. Lane (r,kc)
//      holds i,f,g,o of (row, d) in acc[rg][tt][0..3]. Zero-shuffle LSTM.
// ===========================================================================
template<int KS, int RG, bool LIT>
__global__ __launch_bounds__(512, 4) void fused_round(
    const int* __restrict__ ptr, const int* __restrict__ col,
    const unsigned short* __restrict__ Tsrc,
    const unsigned short* hold, unsigned short* hnew,   // may alias (C side)
    unsigned short* __restrict__ cst,                   // bf16 cell state
    const unsigned short* __restrict__ Wp, const float* __restrict__ bP,
    const unsigned short* __restrict__ Wm1, const float* __restrict__ bm1,
    const unsigned short* __restrict__ Wm2, const float* __restrict__ bm2,
    const unsigned short* __restrict__ Wm3, const float* __restrict__ bm3,
    unsigned short* __restrict__ Tout) {
  constexpr int ROWS = RG * 16;
  __shared__ __align__(16) unsigned short msg[ROWS][136];
  __shared__ __align__(16) unsigned short hsA[ROWS][136];
  __shared__ __align__(16) unsigned short hsF[LIT ? ROWS : 1][136];
  __shared__ __align__(16) unsigned short xb[ROWS][136];
  __shared__ __align__(16) unsigned short pmsg[RG == 1 ? 3 : 1][RG == 1 ? 16 : 1][136];
  const int tid = threadIdx.x;
  const int w = tid >> 6, l = tid & 63;
  const int r = l & 15, kc = l >> 4;
  const int row0 = blockIdx.x * ROWS;

  // ---- early-issue: h staging loads into regs (threads 256+) ----
  uint4 stA[2], stF[2];
  if (tid >= 256) {
    const int sidx = tid - 256;
#pragma unroll
    for (int q = 0; q < RG; ++q) {
      const int n = sidx + q * 256;          // ROWS x 16 uint4 slots
      const int rw = n >> 4, c8 = (n & 15) * 8;
      stA[q] = *reinterpret_cast<const uint4*>(&hold[(size_t)(row0 + rw) * 128 + c8]);
      if (LIT) {
        const int gr = row0 + rw;
        const int fr = (gr < N_VARS) ? gr + N_VARS : gr - N_VARS;
        stF[q] = *reinterpret_cast<const uint4*>(&hold[(size_t)fr * 128 + c8]);
      }
    }
  }

  // ---- phase 1a: split gather (8-lane groups, 16 dims/lane), fp32 regs ----
  float s[16];
  {
    const int g8 = tid >> 3, gl = tid & 7;
    const int grow = (RG == 2) ? (g8 & 31) : (g8 & 15);
    const int part = (RG == 2) ? (g8 >> 5) : (g8 >> 4);
    constexpr int NPART = (RG == 2) ? 2 : 4;
    const int row = row0 + grow;
    const int b = ptr[row], e = ptr[row + 1];
#pragma unroll
    for (int q = 0; q < 16; ++q) s[q] = 0.f;
    int j = b + part;
    int c0 = (j < e) ? col[j] : 0;
    while (j < e) {
      const int jn = j + NPART;
      const int c1 = (jn < e) ? col[jn] : 0;
      const unsigned short* src = &Tsrc[(size_t)c0 * 128 + gl * 16];
      const uint4 v0 = *reinterpret_cast<const uint4*>(src);
      const uint4 v1 = *reinterpret_cast<const uint4*>(src + 8);
      s[0]  += bflo(v0.x); s[1]  += bfhi(v0.x);
      s[2]  += bflo(v0.y); s[3]  += bfhi(v0.y);
      s[4]  += bflo(v0.z); s[5]  += bfhi(v0.z);
      s[6]  += bflo(v0.w); s[7]  += bfhi(v0.w);
      s[8]  += bflo(v1.x); s[9]  += bfhi(v1.x);
      s[10] += bflo(v1.y); s[11] += bfhi(v1.y);
      s[12] += bflo(v1.z); s[13] += bfhi(v1.z);
      s[14] += bflo(v1.w); s[15] += bfhi(v1.w);
      j = jn; c0 = c1;
    }
    if (part > 0) {    // write bf16 partial
      uint4 o0, o1;
      o0.x = pack2(s[0], s[1]);  o0.y = pack2(s[2], s[3]);
      o0.z = pack2(s[4], s[5]);  o0.w = pack2(s[6], s[7]);
      o1.x = pack2(s[8], s[9]);  o1.y = pack2(s[10], s[11]);
      o1.z = pack2(s[12], s[13]); o1.w = pack2(s[14], s[15]);
      unsigned short* dst = (RG == 2) ? &msg[grow][gl * 16]
                                      : &pmsg[part - 1][grow][gl * 16];
      *reinterpret_cast<uint4*>(dst) = o0;
      *reinterpret_cast<uint4*>(dst + 8) = o1;
    }
  }
  __syncthreads();

  // ---- phase 1b: part 0 combines; threads 256+ write staged h ----
  {
    const int g8 = tid >> 3, gl = tid & 7;
    const int grow = (RG == 2) ? (g8 & 31) : (g8 & 15);
    const int part = (RG == 2) ? (g8 >> 5) : (g8 >> 4);
    if (part == 0) {
      if (RG == 2) {
        const uint4 m0 = *reinterpret_cast<const uint4*>(&msg[grow][gl * 16]);
        const uint4 m1 = *reinterpret_cast<const uint4*>(&msg[grow][gl * 16 + 8]);
        s[0]  += bflo(m0.x); s[1]  += bfhi(m0.x);
        s[2]  += bflo(m0.y); s[3]  += bfhi(m0.y);
        s[4]  += bflo(m0.z); s[5]  += bfhi(m0.z);
        s[6]  += bflo(m0.w); s[7]  += bfhi(m0.w);
        s[8]  += bflo(m1.x); s[9]  += bfhi(m1.x);
        s[10] += bflo(m1.y); s[11] += bfhi(m1.y);
        s[12] += bflo(m1.z); s[13] += bfhi(m1.z);
        s[14] += bflo(m1.w); s[15] += bfhi(m1.w);
      } else {
#pragma unroll
        for (int p = 0; p < 3; ++p) {
          const uint4 m0 = *reinterpret_cast<const uint4*>(&pmsg[p][grow][gl * 16]);
          const uint4 m1 = *reinterpret_cast<const uint4*>(&pmsg[p][grow][gl * 16 + 8]);
          s[0]  += bflo(m0.x); s[1]  += bfhi(m0.x);
          s[2]  += bflo(m0.y); s[3]  += bfhi(m0.y);
          s[4]  += bflo(m0.z); s[5]  += bfhi(m0.z);
          s[6]  += bflo(m0.w); s[7]  += bfhi(m0.w);
          s[8]  += bflo(m1.x); s[9]  += bfhi(m1.x);
          s[10] += bflo(m1.y); s[11] += bfhi(m1.y);
          s[12] += bflo(m1.z); s[13] += bfhi(m1.z);
          s[14] += bflo(m1.w); s[15] += bfhi(m1.w);
        }
      }
      uint4 o0, o1;
      o0.x = pack2(s[0], s[1]);  o0.y = pack2(s[2], s[3]);
      o0.z = pack2(s[4], s[5]);  o0.w = pack2(s[6], s[7]);
      o1.x = pack2(s[8], s[9]);  o1.y = pack2(s[10], s[11]);
      o1.z = pack2(s[12], s[13]); o1.w = pack2(s[14], s[15]);
      *reinterpret_cast<uint4*>(&msg[grow][gl * 16]) = o0;
      *reinterpret_cast<uint4*>(&msg[grow][gl * 16 + 8]) = o1;
    } else if (tid >= 256) {
      const int sidx = tid - 256;
#pragma unroll
      for (int q = 0; q < RG; ++q) {
        const int n = sidx + q * 256;
        const int rw = n >> 4, c8 = (n & 15) * 8;
        *reinterpret_cast<uint4*>(&hsA[rw][c8]) = stA[q];
        if (LIT)
          *reinterpret_cast<uint4*>(&hsF[rw][c8]) = stF[q];
      }
    }
  }
  __syncthreads();

  // ---- phase 2: gates GEMM (tiled W, 1KB bursts) ----
  f32x4 acc[RG][4];
#pragma unroll
  for (int rg = 0; rg < RG; ++rg)
#pragma unroll
    for (int t = 0; t < 4; ++t) acc[rg][t] = (f32x4){0.f, 0.f, 0.f, 0.f};

#pragma unroll
  for (int ks = 0; ks < KS; ++ks) {
    bf16x8 bfr[RG];
#pragma unroll
    for (int rg = 0; rg < RG; ++rg) {
      const int xr = rg * 16 + r;
      if (ks < 4)        bfr[rg] = ld_frag(&msg[xr][ks * 32 + kc * 8]);
      else if (!LIT)     bfr[rg] = ld_frag(&hsA[xr][(ks - 4) * 32 + kc * 8]);
      else if (ks < 8)   bfr[rg] = ld_frag(&hsF[xr][(ks - 4) * 32 + kc * 8]);
      else               bfr[rg] = ld_frag(&hsA[xr][(ks - 8) * 32 + kc * 8]);
    }
#pragma unroll
    for (int tt = 0; tt < 4; ++tt) {
      bf16x8 afr = ld_frag(&Wp[(size_t)(((w * KS + ks) * 4 + tt) * 64 + l) * 8]);
#pragma unroll
      for (int rg = 0; rg < RG; ++rg)
        acc[rg][tt] = __builtin_amdgcn_mfma_f32_16x16x32_bf16(afr, bfr[rg], acc[rg][tt], 0, 0, 0);
    }
  }
  __syncthreads();   // all LDS reads done before hsA overwrite

  // ---- LSTM epilogue (zero-shuffle; c is bf16) ----
  {
    const int d0 = w * 16 + kc * 4;
#pragma unroll
    for (int rg = 0; rg < RG; ++rg) {
      const int row = row0 + rg * 16 + r;
      const size_t cb = (size_t)row * 128 + d0;
      const uint2 cv2 = *reinterpret_cast<const uint2*>(&cst[cb]);
      const float cpv[4] = {bflo(cv2.x), bfhi(cv2.x), bflo(cv2.y), bfhi(cv2.y)};
      unsigned int cp2[2], hp[2];
#pragma unroll
      for (int tt = 0; tt < 4; ++tt) {
        const float4 bb = *reinterpret_cast<const float4*>(&bP[w * 64 + tt * 16 + kc * 4]);
        float ig = acc[rg][tt][0] + bb.x;
        float fg = acc[rg][tt][1] + bb.y;
        float gg = acc[rg][tt][2] + bb.z;
        float og = acc[rg][tt][3] + bb.w;
        float cn = fast_sigmoid(fg) * cpv[tt] + fast_sigmoid(ig) * fast_tanh(gg);
        float hv = fast_sigmoid(og) * fast_tanh(cn);
        if (tt & 1) { cp2[tt >> 1] |= (unsigned int)f2bf(cn) << 16;
                      hp[tt >> 1]  |= (unsigned int)f2bf(hv) << 16; }
        else        { cp2[tt >> 1]  = (unsigned int)f2bf(cn);
                      hp[tt >> 1]   = (unsigned int)f2bf(hv); }
      }
      uint2 cw = {cp2[0], cp2[1]};
      *reinterpret_cast<uint2*>(&cst[cb]) = cw;
      uint2 hv2 = {hp[0], hp[1]};
      *reinterpret_cast<uint2*>(&hnew[cb]) = hv2;
      *reinterpret_cast<uint2*>(&hsA[rg * 16 + r][d0]) = hv2;
    }
  }
  __syncthreads();

  // ---- phase 3: 3-layer MLP; wave w = col-tile w, rg looped (Wm read 1x) ----
  {
    f32x4 a2[RG];
#pragma unroll
    for (int rg = 0; rg < RG; ++rg) a2[rg] = (f32x4){0.f, 0.f, 0.f, 0.f};
#pragma unroll
    for (int ks = 0; ks < 4; ++ks) {
      bf16x8 bf = ld_frag(&Wm1[(size_t)((w * 4 + ks) * 64 + l) * 8]);
#pragma unroll
      for (int rg = 0; rg < RG; ++rg) {
        bf16x8 af = ld_frag(&hsA[rg * 16 + r][ks * 32 + kc * 8]);
        a2[rg] = __builtin_amdgcn_mfma_f32_16x16x32_bf16(af, bf, a2[rg], 0, 0, 0);
      }
    }
    float bv = bm1[w * 16 + r];
#pragma unroll
    for (int rg = 0; rg < RG; ++rg)
#pragma unroll
      for (int j = 0; j < 4; ++j)
        xb[rg * 16 + kc * 4 + j][w * 16 + r] = f2bf(fmaxf(a2[rg][j] + bv, 0.f));
  }
  __syncthreads();
  {
    f32x4 a2[RG];
#pragma unroll
    for (int rg = 0; rg < RG; ++rg) a2[rg] = (f32x4){0.f, 0.f, 0.f, 0.f};
#pragma unroll
    for (int ks = 0; ks < 4; ++ks) {
      bf16x8 bf = ld_frag(&Wm2[(size_t)((w * 4 + ks) * 64 + l) * 8]);
#pragma unroll
      for (int rg = 0; rg < RG; ++rg) {
        bf16x8 af = ld_frag(&xb[rg * 16 + r][ks * 32 + kc * 8]);
        a2[rg] = __builtin_amdgcn_mfma_f32_16x16x32_bf16(af, bf, a2[rg], 0, 0, 0);
      }
    }
    float bv = bm2[w * 16 + r];
    __syncthreads();
#pragma unroll
    for (int rg = 0; rg < RG; ++rg)
#pragma unroll
      for (int j = 0; j < 4; ++j)
        msg[rg * 16 + kc * 4 + j][w * 16 + r] = f2bf(fmaxf(a2[rg][j] + bv, 0.f));
  }
  __syncthreads();
  {
    f32x4 a2[RG];
#pragma unroll
    for (int rg = 0; rg < RG; ++rg) a2[rg] = (f32x4){0.f, 0.f, 0.f, 0.f};
#pragma unroll
    for (int ks = 0; ks < 4; ++ks) {
      bf16x8 bf = ld_frag(&Wm3[(size_t)((w * 4 + ks) * 64 + l) * 8]);
#pragma unroll
      for (int rg = 0; rg < RG; ++rg) {
        bf16x8 af = ld_frag(&msg[rg * 16 + r][ks * 32 + kc * 8]);
        a2[rg] = __builtin_amdgcn_mfma_f32_16x16x32_bf16(af, bf, a2[rg], 0, 0, 0);
      }
    }
    float bv = bm3[w * 16 + r];
#pragma unroll
    for (int rg = 0; rg < RG; ++rg)
#pragma unroll
      for (int j = 0; j < 4; ++j)
        Tout[(size_t)(row0 + rg * 16 + kc * 4 + j) * 128 + w * 16 + r] =
            f2bf(a2[rg][j] + bv);
  }
}

// ---------------------------------------------------------------------------
// Prologue 3-layer MLP (tiled weights): 256 thr = 4 waves, 64 rows/block.
// ---------------------------------------------------------------------------
__global__ __launch_bounds__(256) void fused_mlp3(
    const unsigned short* __restrict__ A,
    const unsigned short* __restrict__ W1, const float* __restrict__ b1,
    const unsigned short* __restrict__ W2, const float* __restrict__ b2,
    const unsigned short* __restrict__ W3, const float* __restrict__ b3,
    unsigned short* __restrict__ out) {
  __shared__ __align__(16) unsigned short xbuf[2][4][16][136];
  const int w = threadIdx.x >> 6, l = threadIdx.x & 63;
  const int r = l & 15, kc = l >> 4;
  const int row0 = blockIdx.x * 64 + w * 16;

  f32x4 acc[8];
#pragma unroll
  for (int t = 0; t < 8; ++t) acc[t] = (f32x4){0.f, 0.f, 0.f, 0.f};
#pragma unroll
  for (int ks = 0; ks < 4; ++ks) {
    bf16x8 a = ld_frag(&A[(size_t)(row0 + r) * 128 + ks * 32 + kc * 8]);
#pragma unroll
    for (int t = 0; t < 8; ++t) {
      bf16x8 b = ld_frag(&W1[(size_t)((t * 4 + ks) * 64 + l) * 8]);
      acc[t] = __builtin_amdgcn_mfma_f32_16x16x32_bf16(a, b, acc[t], 0, 0, 0);
    }
  }
#pragma unroll
  for (int t = 0; t < 8; ++t) {
    float bv = b1[t * 16 + r];
#pragma unroll
    for (int j = 0; j < 4; ++j)
      xbuf[0][w][kc * 4 + j][t * 16 + r] = f2bf(fmaxf(acc[t][j] + bv, 0.f));
  }
#pragma unroll
  for (int t = 0; t < 8; ++t) acc[t] = (f32x4){0.f, 0.f, 0.f, 0.f};
#pragma unroll
  for (int ks = 0; ks < 4; ++ks) {
    bf16x8 a = ld_frag(&xbuf[0][w][r][ks * 32 + kc * 8]);
#pragma unroll
    for (int t = 0; t < 8; ++t) {
      bf16x8 b = ld_frag(&W2[(size_t)((t * 4 + ks) * 64 + l) * 8]);
      acc[t] = __builtin_amdgcn_mfma_f32_16x16x32_bf16(a, b, acc[t], 0, 0, 0);
    }
  }
#pragma unroll
  for (int t = 0; t < 8; ++t) {
    float bv = b2[t * 16 + r];
#pragma unroll
    for (int j = 0; j < 4; ++j)
      xbuf[1][w][kc * 4 + j][t * 16 + r] = f2bf(fmaxf(acc[t][j] + bv, 0.f));
  }
#pragma unroll
  for (int t = 0; t < 8; ++t) acc[t] = (f32x4){0.f, 0.f, 0.f, 0.f};
#pragma unroll
  for (int ks = 0; ks < 4; ++ks) {
    bf16x8 a = ld_frag(&xbuf[1][w][r][ks * 32 + kc * 8]);
#pragma unroll
    for (int t = 0; t < 8; ++t) {
      bf16x8 b = ld_frag(&W3[(size_t)((t * 4 + ks) * 64 + l) * 8]);
      acc[t] = __builtin_amdgcn_mfma_f32_16x16x32_bf16(a, b, acc[t], 0, 0, 0);
    }
  }
#pragma unroll
  for (int t = 0; t < 8; ++t) {
    float bv = b3[t * 16 + r];
#pragma unroll
    for (int j = 0; j < 4; ++j)
      out[(size_t)(row0 + kc * 4 + j) * 128 + t * 16 + r] = f2bf(acc[t][j] + bv);
  }
}

// ---------------------------------------------------------------------------
// Fused vote (tiled weights).
// ---------------------------------------------------------------------------
__global__ __launch_bounds__(256) void fused_vote(
    const unsigned short* __restrict__ A,
    const unsigned short* __restrict__ W1, const float* __restrict__ b1,
    const unsigned short* __restrict__ W2, const float* __restrict__ b2,
    const float* __restrict__ w3, const float* __restrict__ b3,
    float* __restrict__ vote) {
  __shared__ __align__(16) unsigned short xbuf[4][16][136];
  const int w = threadIdx.x >> 6, l = threadIdx.x & 63;
  const int r = l & 15, kc = l >> 4;
  const int row0 = blockIdx.x * 64 + w * 16;

  f32x4 acc[8];
#pragma unroll
  for (int t = 0; t < 8; ++t) acc[t] = (f32x4){0.f, 0.f, 0.f, 0.f};
#pragma unroll
  for (int ks = 0; ks < 4; ++ks) {
    bf16x8 a = ld_frag(&A[(size_t)(row0 + r) * 128 + ks * 32 + kc * 8]);
#pragma unroll
    for (int t = 0; t < 8; ++t) {
      bf16x8 b = ld_frag(&W1[(size_t)((t * 4 + ks) * 64 + l) * 8]);
      acc[t] = __builtin_amdgcn_mfma_f32_16x16x32_bf16(a, b, acc[t], 0, 0, 0);
    }
  }
#pragma unroll
  for (int t = 0; t < 8; ++t) {
    float bv = b1[t * 16 + r];
#pragma unroll
    for (int j = 0; j < 4; ++j)
      xbuf[w][kc * 4 + j][t * 16 + r] = f2bf(fmaxf(acc[t][j] + bv, 0.f));
  }
#pragma unroll
  for (int t = 0; t < 8; ++t) acc[t] = (f32x4){0.f, 0.f, 0.f, 0.f};
#pragma unroll
  for (int ks = 0; ks < 4; ++ks) {
    bf16x8 a = ld_frag(&xbuf[w][r][ks * 32 + kc * 8]);
#pragma unroll
    for (int t = 0; t < 8; ++t) {
      bf16x8 b = ld_frag(&W2[(size_t)((t * 4 + ks) * 64 + l) * 8]);
      acc[t] = __builtin_amdgcn_mfma_f32_16x16x32_bf16(a, b, acc[t], 0, 0, 0);
    }
  }
  float vs[4] = {0.f, 0.f, 0.f, 0.f};
#pragma unroll
  for (int t = 0; t < 8; ++t) {
    float bv = b2[t * 16 + r], wv = w3[t * 16 + r];
#pragma unroll
    for (int j = 0; j < 4; ++j)
      vs[j] += fmaxf(acc[t][j] + bv, 0.f) * wv;
  }
#pragma unroll
  for (int off = 1; off < 16; off <<= 1) {
#pragma unroll
    for (int j = 0; j < 4; ++j) vs[j] += __shfl_xor(vs[j], off, 16);
  }
  if (r == 0) {
#pragma unroll
    for (int j = 0; j < 4; ++j) vote[row0 + kc * 4 + j] = vs[j] + b3[0];
  }
}

// ---------------------------------------------------------------------------
// One-time prep (c state is bf16).
// ---------------------------------------------------------------------------
__global__ void init_state_kernel(const float* __restrict__ Lw, const float* __restrict__ Lb,
                                  const float* __restrict__ Cw, const float* __restrict__ Cb,
                                  unsigned short* __restrict__ Lh, unsigned short* __restrict__ Lc,
                                  unsigned short* __restrict__ Ch, unsigned short* __restrict__ Cc) {
  int idx = blockIdx.x * 256 + threadIdx.x;
  if (idx >= N_CLAUSES * DIM) return;
  int d = idx & 127;
  Ch[idx] = f2bf(Cw[d] + Cb[d]);
  Cc[idx] = 0;
  if (idx < N_LITS * DIM) {
    Lh[idx] = f2bf(Lw[d] + Lb[d]);
    Lc[idx] = 0;
  }
}

// 8 fp32 [128,128] matrices -> bf16 tile-packed (tile id = tt*4+ks).
__global__ void pack8_kernel(const float* s0, const float* s1, const float* s2, const float* s3,
                             const float* s4, const float* s5, const float* s6, const float* s7,
                             unsigned short* d0, unsigned short* d1, unsigned short* d2,
                             unsigned short* d3, unsigned short* d4, unsigned short* d5,
                             unsigned short* d6, unsigned short* d7) {
  int i = blockIdx.x * 256 + threadIdx.x;   // [0, 16384)
  const float* s; unsigned short* d;
  switch (blockIdx.y) {
    case 0: s = s0; d = d0; break;
    case 1: s = s1; d = d1; break;
    case 2: s = s2; d = d2; break;
    case 3: s = s3; d = d3; break;
    case 4: s = s4; d = d4; break;
    case 5: s = s5; d = d5; break;
    case 6: s = s6; d = d6; break;
    default: s = s7; d = d7; break;
  }
  int np = i >> 7, k = i & 127;
  int tt = np >> 4, r = np & 15;
  int ks = k >> 5, kcf = (k >> 3) & 3, e = k & 7;
  int dst = (((tt * 4 + ks) * 64) + kcf * 16 + r) * 8 + e;
  d[dst] = f2bf(s[i]);
}

// Gate-permuted + tile-packed LSTM weight pack (8-wave layout):
// np = w*64 + tt*16 + kc*4 + j <-> gate j, dim d = w*16 + kc*4 + tt.
// dest tile id = (w*KS + ks)*4 + tt, lane = kcf*16 + (np&15).
template<int KIH>
__global__ void pack_gates_kernel(const float* __restrict__ wih, const float* __restrict__ whh,
                                  const float* __restrict__ bih, const float* __restrict__ bhh,
                                  unsigned short* __restrict__ Wp, float* __restrict__ bP) {
  constexpr int K = KIH + 128;
  constexpr int KS = K / 32;
  int idx = blockIdx.x * 256 + threadIdx.x;
  if (idx >= 512 * K) return;
  int np = idx / K, k = idx % K;
  int gt = np & 3;
  int d = ((np >> 6) << 4) + (((np >> 2) & 3) << 2) + ((np >> 4) & 3);
  int orig = gt * 128 + d;
  float v = (k < KIH) ? wih[(size_t)orig * KIH + k] : whh[(size_t)orig * 128 + (k - KIH)];
  int w = np >> 6, tt = (np >> 4) & 3, rr = np & 15;
  int ks = k >> 5, kcf = (k >> 3) & 3, e = k & 7;
  size_t dst = ((size_t)((w * KS + ks) * 4 + tt) * 64 + kcf * 16 + rr) * 8 + e;
  Wp[dst] = f2bf(v);
  if (k == 0) bP[np] = bih[orig] + bhh[orig];
}

// ---------------------------------------------------------------------------
// CSR build.
// ---------------------------------------------------------------------------
__global__ void count_kernel(const int* __restrict__ uidx,
                             int* __restrict__ lit_cnt, int* __restrict__ cls_cnt) {
  int i = blockIdx.x * 256 + threadIdx.x;
  if (i < N_CELLS) {
    atomicAdd(&lit_cnt[uidx[2 * i]], 1);
    atomicAdd(&cls_cnt[uidx[2 * i + 1]], 1);
  }
}

__global__ void scan_kernel(const int* __restrict__ cnt, int* __restrict__ ptr, int n) {
  __shared__ int part[1024];
  __shared__ int total;
  int t = threadIdx.x;
  int chunk = (n + 1023) >> 10;
  int lo = t * chunk, hi = min(lo + chunk, n);
  int s = 0;
  for (int i = lo; i < hi; ++i) s += cnt[i];
  part[t] = s;
  __syncthreads();
  if (t == 0) {
    int acc = 0;
    for (int i = 0; i < 1024; ++i) { int v = part[i]; part[i] = acc; acc += v; }
    total = acc;
  }
  __syncthreads();
  int acc = part[t];
  for (int i = lo; i < hi; ++i) { ptr[i] = acc; acc += cnt[i]; }
  if (t == 0) ptr[n] = total;
}

__global__ void scatter_kernel(const int* __restrict__ uidx,
                               const int* __restrict__ lit_ptr, const int* __restrict__ cls_ptr,
                               int* __restrict__ lit_fill, int* __restrict__ cls_fill,
                               int* __restrict__ lit_col, int* __restrict__ cls_col) {
  int i = blockIdx.x * 256 + threadIdx.x;
  if (i < N_CELLS) {
    int lit = uidx[2 * i], cls = uidx[2 * i + 1];
    int p = atomicAdd(&lit_fill[lit], 1);
    lit_col[lit_ptr[lit] + p] = cls;
    int q = atomicAdd(&cls_fill[cls], 1);
    cls_col[cls_ptr[cls] + q] = lit;
  }
}

__global__ void prob_mean_kernel(const float* __restrict__ vote, float* __restrict__ out) {
  int p = blockIdx.x;
  int t = threadIdx.x;
  float s = 0.f;
  for (int i = t; i < 500; i += 256) s += vote[p * 500 + i] + vote[N_VARS + p * 500 + i];
  __shared__ float red[256];
  red[t] = s;
  __syncthreads();
  for (int off = 128; off > 0; off >>= 1) {
    if (t < off) red[t] += red[t + off];
    __syncthreads();
  }
  if (t == 0) out[p] = red[0] * (1.0f / 1000.0f);
}

// ---------------------------------------------------------------------------
extern "C" void kernel_launch(void* const* d_in, const int* in_sizes, int n_in,
                              void* d_out, int out_size, void* d_ws, size_t ws_size,
                              hipStream_t stream) {
  (void)in_sizes; (void)n_in; (void)out_size;
  const int* uidx = (const int*)d_in[0];
  const float* L_init_w = (const float*)d_in[4];
  const float* L_init_b = (const float*)d_in[5];
  const float* C_init_w = (const float*)d_in[6];
  const float* C_init_b = (const float*)d_in[7];
  const float* Lmsg_w1 = (const float*)d_in[8],  *Lmsg_b1 = (const float*)d_in[9];
  const float* Lmsg_w2 = (const float*)d_in[10], *Lmsg_b2 = (const float*)d_in[11];
  const float* Lmsg_w3 = (const float*)d_in[12], *Lmsg_b3 = (const float*)d_in[13];
  const float* Cmsg_w1 = (const float*)d_in[14], *Cmsg_b1 = (const float*)d_in[15];
  const float* Cmsg_w2 = (const float*)d_in[16], *Cmsg_b2 = (const float*)d_in[17];
  const float* Cmsg_w3 = (const float*)d_in[18], *Cmsg_b3 = (const float*)d_in[19];
  const float* Lvote_w1 = (const float*)d_in[20], *Lvote_b1 = (const float*)d_in[21];
  const float* Lvote_w2 = (const float*)d_in[22], *Lvote_b2 = (const float*)d_in[23];
  const float* Lvote_w3 = (const float*)d_in[24], *Lvote_b3 = (const float*)d_in[25];
  const float* Lu_wih = (const float*)d_in[26], *Lu_whh = (const float*)d_in[27];
  const float* Lu_bih = (const float*)d_in[28], *Lu_bhh = (const float*)d_in[29];
  const float* Cu_wih = (const float*)d_in[30], *Cu_whh = (const float*)d_in[31];
  const float* Cu_bih = (const float*)d_in[32], *Cu_bhh = (const float*)d_in[33];
  float* out = (float*)d_out;

  // ---- workspace carve-up ----
  char* base = (char*)d_ws;
  size_t off = 0;
  auto alloc = [&](size_t bytes) {
    void* p = base + off;
    off = (off + bytes + 255) & ~(size_t)255;
    return p;
  };
  unsigned short* Lc = (unsigned short*)alloc((size_t)N_LITS * DIM * 2);
  unsigned short* Cc = (unsigned short*)alloc((size_t)N_CLAUSES * DIM * 2);
  float* bL   = (float*)alloc(512 * 4);
  float* bC   = (float*)alloc(512 * 4);
  float* vote = (float*)alloc(N_LITS * 4);
  unsigned short* LhA = (unsigned short*)alloc((size_t)N_LITS * DIM * 2);
  unsigned short* LhB = (unsigned short*)alloc((size_t)N_LITS * DIM * 2);
  unsigned short* Ch  = (unsigned short*)alloc((size_t)N_CLAUSES * DIM * 2);
  unsigned short* TL  = (unsigned short*)alloc((size_t)N_LITS * DIM * 2);
  unsigned short* TC  = (unsigned short*)alloc((size_t)N_CLAUSES * DIM * 2);
  unsigned short* WLp = (unsigned short*)alloc(512 * 384 * 2);
  unsigned short* WCp = (unsigned short*)alloc(512 * 256 * 2);
  unsigned short* wLm1 = (unsigned short*)alloc(DIM * DIM * 2);
  unsigned short* wLm2 = (unsigned short*)alloc(DIM * DIM * 2);
  unsigned short* wLm3 = (unsigned short*)alloc(DIM * DIM * 2);
  unsigned short* wCm1 = (unsigned short*)alloc(DIM * DIM * 2);
  unsigned short* wCm2 = (unsigned short*)alloc(DIM * DIM * 2);
  unsigned short* wCm3 = (unsigned short*)alloc(DIM * DIM * 2);
  unsigned short* wV1  = (unsigned short*)alloc(DIM * DIM * 2);
  unsigned short* wV2  = (unsigned short*)alloc(DIM * DIM * 2);
  int* lit_cnt  = (int*)alloc(N_LITS * 4);
  int* cls_cnt  = (int*)alloc(N_CLAUSES * 4);
  int* lit_fill = (int*)alloc(N_LITS * 4);
  int* cls_fill = (int*)alloc(N_CLAUSES * 4);
  int* lit_ptr  = (int*)alloc((N_LITS + 1) * 4);
  int* cls_ptr  = (int*)alloc((N_CLAUSES + 1) * 4);
  int* lit_col  = (int*)alloc(N_CELLS * 4);
  int* cls_col  = (int*)alloc(N_CELLS * 4);
  if (off > ws_size) return;

  // ---- CSR build (redone every launch) ----
  hipMemsetAsync(lit_cnt, 0, (char*)lit_ptr - (char*)lit_cnt, stream);
  count_kernel<<<(N_CELLS + 255) / 256, 256, 0, stream>>>(uidx, lit_cnt, cls_cnt);
  scan_kernel<<<1, 1024, 0, stream>>>(lit_cnt, lit_ptr, N_LITS);
  scan_kernel<<<1, 1024, 0, stream>>>(cls_cnt, cls_ptr, N_CLAUSES);
  scatter_kernel<<<(N_CELLS + 255) / 256, 256, 0, stream>>>(
      uidx, lit_ptr, cls_ptr, lit_fill, cls_fill, lit_col, cls_col);

  // ---- one-time weight conversion / packing / state init ----
  init_state_kernel<<<(N_CLAUSES * DIM + 255) / 256, 256, 0, stream>>>(
      L_init_w, L_init_b, C_init_w, C_init_b, LhA, Lc, Ch, Cc);
  pack_gates_kernel<256><<<(512 * 384 + 255) / 256, 256, 0, stream>>>(
      Lu_wih, Lu_whh, Lu_bih, Lu_bhh, WLp, bL);
  pack_gates_kernel<128><<<(512 * 256 + 255) / 256, 256, 0, stream>>>(
      Cu_wih, Cu_whh, Cu_bih, Cu_bhh, WCp, bC);
  dim3 cgrid(DIM * DIM / 256, 8);
  pack8_kernel<<<cgrid, 256, 0, stream>>>(
      Lmsg_w1, Lmsg_w2, Lmsg_w3, Cmsg_w1, Cmsg_w2, Cmsg_w3, Lvote_w1, Lvote_w2,
      wLm1, wLm2, wLm3, wCm1, wCm2, wCm3, wV1, wV2);

  // ---- prologue: T_L = L-MLP(Lh0) ----
  fused_mlp3<<<N_LITS / 64, 256, 0, stream>>>(
      LhA, wLm1, Lmsg_b1, wLm2, Lmsg_b2, wLm3, Lmsg_b3, TL);

  // ---- message-passing rounds: 2 kernels per round ----
  for (int r = 0; r < N_ROUNDS; ++r) {
    fused_round<8, 2, false><<<N_CLAUSES / 32, 512, 0, stream>>>(
        cls_ptr, cls_col, TL, Ch, Ch, Cc, WCp, bC,
        wCm1, Cmsg_b1, wCm2, Cmsg_b2, wCm3, Cmsg_b3, TC);
    const unsigned short* lold = (r & 1) ? LhB : LhA;
    unsigned short* lnew = (r & 1) ? LhA : LhB;
    fused_round<12, 1, true><<<N_LITS / 16, 512, 0, stream>>>(
        lit_ptr, lit_col, TC, lold, lnew, Lc, WLp, bL,
        wLm1, Lmsg_b1, wLm2, Lmsg_b2, wLm3, Lmsg_b3, TL);
  }
  // after 16 rounds (even count), final Lh is in LhA

  // ---- vote + per-problem mean ----
  fused_vote<<<N_LITS / 64, 256, 0, stream>>>(
      LhA, wV1, Lvote_b1, wV2, Lvote_b2, Lvote_w3, Lvote_b3, vote);
  prob_mean_kernel<<<N_PROBS, 256, 0, stream>>>(vote, out);
}